// Round 4
// baseline (272.127 us; speedup 1.0000x reference)
//
#include <hip/hip_runtime.h>

#define BATCH 64
#define HH 512
#define WW 512
#define TH 32          // output rows per block strip
#define KS 11
#define PADK 5
#define NPIX (64.0 * 512.0 * 512.0)
#define LROW (WW + 2 * PADK)   // 522 float2 slots per row
#define NT 256                 // threads per block; each owns 2 columns

// One block: 256 threads, thread t -> cols {2t, 2t+1}; strip of TH=32 rows.
// Stage only float2{a,b} per pixel (8 B/px LDS). Per staged row each thread:
//   - 6 aligned ds_read_b128 covering the 12 float2 cols its 2 outputs need
//   - per-col q=a^2+b^2, p=ab in registers (once per col, not per tap)
//   - horizontal 11-tap conv of 4 signals x 2 cols (88 fma)
// Vertical 11-tap via float2-ring[11] x 4 signals (88 VGPR) with STATIC slots:
// inner 11-phase unroll, dynamic outer loop (code fits I$; round-3 lesson:
// full unroll + tight VGPR cap => scratch spills, 53 MB write traffic).
__global__ void __launch_bounds__(NT, 3) ssim_main_kernel(
    const float* __restrict__ img1, const float* __restrict__ img2,
    double* __restrict__ accum) {
  // Gaussian(sigma=1.5, K=11), normalized (fp64-precomputed).
  constexpr float G[KS] = {
      0.00102838f, 0.00759884f, 0.03600087f, 0.10936069f, 0.21300553f,
      0.26601172f, 0.21300553f, 0.10936069f, 0.03600087f, 0.00759884f,
      0.00102838f};

  const int t  = threadIdx.x;            // 0..255; cols 2t, 2t+1
  const int r0 = blockIdx.x * TH;
  const int b  = blockIdx.y;

  const float* __restrict__ p1 = img1 + (size_t)b * (HH * WW);
  const float* __restrict__ p2 = img2 + (size_t)b * (HH * WW);

  // Double-buffered zero-padded packed row buffers (8.4 KB).
  __shared__ float2 sh[2][LROW];
  if (t < PADK) {
#pragma unroll
    for (int bi = 0; bi < 2; ++bi) {
      sh[bi][t]             = make_float2(0.f, 0.f);
      sh[bi][WW + PADK + t] = make_float2(0.f, 0.f);
    }
  }

  // Vertical ring: slot (i % 11) holds h-conv of input row i; .x/.y = 2 cols.
  float2 rA[KS], rB[KS], rQ[KS], rP[KS];
  float lx = 0.f, ly = 0.f;

  // Prefetch input row i=0 (image row r0-5; rr<HH guaranteed here).
  float2 pa = make_float2(0.f, 0.f), pb = make_float2(0.f, 0.f);
  {
    const int rr = r0 - PADK;
    if (rr >= 0) {
      pa = ((const float2*)(p1 + (size_t)rr * WW))[t];
      pb = ((const float2*)(p2 + (size_t)rr * WW))[t];
    }
  }

  for (int ii = 0; ii < 4; ++ii) {       // dynamic: keeps code ~1 phase x 11
#pragma unroll
    for (int p = 0; p < KS; ++p) {
      const int i = ii * KS + p;         // i % 11 == p (static slot index)
      if (i < TH + 2 * PADK) {           // uniform guard (skips i=42,43)
        const int buf = i & 1;

        // Stage row i from prefetch regs; 2 contiguous b64 writes.
        sh[buf][PADK + 2 * t]     = make_float2(pa.x, pb.x);
        sh[buf][PADK + 2 * t + 1] = make_float2(pa.y, pb.y);

        // Prefetch row i+1 (covered by this phase's ~400 VALU ops).
        {
          const int rn = r0 - PADK + i + 1;
          pa = make_float2(0.f, 0.f);
          pb = make_float2(0.f, 0.f);
          if (rn >= 0 && rn < HH) {
            pa = ((const float2*)(p1 + (size_t)rn * WW))[t];
            pb = ((const float2*)(p2 + (size_t)rn * WW))[t];
          }
        }

        __syncthreads();   // dbuf => one barrier per row

        // Load the 12 cols (slots 2t .. 2t+11) as 6 aligned float4.
        float av[12], bv[12];
        const float4* sh4 = (const float4*)(&sh[buf][0]);
#pragma unroll
        for (int k = 0; k < 6; ++k) {
          const float4 v = sh4[t + k];   // cols 2t-5+2k, 2t-4+2k (padded)
          av[2 * k]     = v.x;  bv[2 * k]     = v.y;
          av[2 * k + 1] = v.z;  bv[2 * k + 1] = v.w;
        }

        // Per-col q = a^2+b^2, p = ab (once per col).
        float qv[12], pv[12];
#pragma unroll
        for (int j = 0; j < 12; ++j) {
          qv[j] = fmaf(av[j], av[j], bv[j] * bv[j]);
          pv[j] = av[j] * bv[j];
        }

        // Horizontal 11-tap conv: 4 signals x 2 cols.
        float2 h1 = make_float2(0.f, 0.f), h2 = h1, hq = h1, hp = h1;
#pragma unroll
        for (int k = 0; k < KS; ++k) {
          const float w = G[k];
          h1.x = fmaf(w, av[k], h1.x);      h1.y = fmaf(w, av[k + 1], h1.y);
          h2.x = fmaf(w, bv[k], h2.x);      h2.y = fmaf(w, bv[k + 1], h2.y);
          hq.x = fmaf(w, qv[k], hq.x);      hq.y = fmaf(w, qv[k + 1], hq.y);
          hp.x = fmaf(w, pv[k], hp.x);      hp.y = fmaf(w, pv[k + 1], hp.y);
        }
        rA[p] = h1; rB[p] = h2; rQ[p] = hq; rP[p] = hp;

        if (i >= 2 * PADK) {   // uniform; true from i=10 on
          // Vertical 11-tap: row (i-10+tp) lives in slot (p+1+tp)%11.
          float2 mu1 = make_float2(0.f, 0.f), mu2 = mu1, mq = mu1, mp = mu1;
#pragma unroll
          for (int tp = 0; tp < KS; ++tp) {
            const int s = (p + 1 + tp) % KS;  // static
            const float w = G[tp];
            mu1.x = fmaf(w, rA[s].x, mu1.x);  mu1.y = fmaf(w, rA[s].y, mu1.y);
            mu2.x = fmaf(w, rB[s].x, mu2.x);  mu2.y = fmaf(w, rB[s].y, mu2.y);
            mq.x  = fmaf(w, rQ[s].x, mq.x);   mq.y  = fmaf(w, rQ[s].y, mq.y);
            mp.x  = fmaf(w, rP[s].x, mp.x);   mp.y  = fmaf(w, rP[s].y, mp.y);
          }
          const float C1 = 1e-4f, C2 = 9e-4f;
          {
            const float m1s = mu1.x * mu1.x, m2s = mu2.x * mu2.x;
            const float m12 = mu1.x * mu2.x;
            const float s12 = mp.x - m12;
            const float sqq = mq.x - m1s - m2s;
            const float num = fmaf(2.f, m12, C1) * fmaf(2.f, s12, C2);
            const float den = (m1s + m2s + C1) * (sqq + C2);
            lx = fmaf(num, __builtin_amdgcn_rcpf(den), lx);
          }
          {
            const float m1s = mu1.y * mu1.y, m2s = mu2.y * mu2.y;
            const float m12 = mu1.y * mu2.y;
            const float s12 = mp.y - m12;
            const float sqq = mq.y - m1s - m2s;
            const float num = fmaf(2.f, m12, C1) * fmaf(2.f, s12, C2);
            const float den = (m1s + m2s + C1) * (sqq + C2);
            ly = fmaf(num, __builtin_amdgcn_rcpf(den), ly);
          }
        }
      }
    }
  }

  float local = lx + ly;

  // Block reduction: wave64 shuffle -> LDS -> one double atomic per block.
#pragma unroll
  for (int off = 32; off > 0; off >>= 1) local += __shfl_down(local, off, 64);

  __shared__ float wsum[NT / 64];
  const int wave = threadIdx.x >> 6;
  const int lane = threadIdx.x & 63;
  if (lane == 0) wsum[wave] = local;
  __syncthreads();
  if (threadIdx.x == 0) {
    float s = 0.f;
#pragma unroll
    for (int w = 0; w < NT / 64; ++w) s += wsum[w];
    atomicAdd(accum, (double)s);
  }
}

__global__ void ssim_final_kernel(const double* __restrict__ accum,
                                  float* __restrict__ out) {
  out[0] = 1.0f - (float)(accum[0] / NPIX);
}

extern "C" void kernel_launch(void* const* d_in, const int* in_sizes, int n_in,
                              void* d_out, int out_size, void* d_ws, size_t ws_size,
                              hipStream_t stream) {
  const float* img1 = (const float*)d_in[0];
  const float* img2 = (const float*)d_in[1];
  double* accum = (double*)d_ws;
  hipMemsetAsync(accum, 0, sizeof(double), stream);

  dim3 grid(HH / TH, BATCH);
  ssim_main_kernel<<<grid, NT, 0, stream>>>(img1, img2, accum);
  ssim_final_kernel<<<1, 1, 0, stream>>>(accum, (float*)d_out);
}